// Round 4
// baseline (517.290 us; speedup 1.0000x reference)
//
#include <hip/hip_runtime.h>
#include <stdint.h>

#define HW (512 * 512)
#define NBINS 256
#define NB 128
#define NCOPY 8
#define HSTR 257           // copy stride: 257 % 32 = 1 -> rotates banks per copy
#define CHUNKS 32          // 16 rows per chunk
#define CPX4 2048          // float4s (= 8192 pixels) per chunk

// ---------------- workspace layout (bytes) ----------------
// 0      : counts[256]   int   (per-bin totals, batch-independent)
// 1024   : S1[128][256]  float
// 132096 : S2[128][256]  float
// total  : 263168

// Native non-returning LDS float atomic add. HIP's atomicAdd on __shared__
// float lowers to a ds_read+ds_cmpst CAS retry loop (~250 cy dependent chain
// per call -- measured rounds 1/3); ds_add_f32 is fire-and-forget.
// addr = LDS byte offset (low 32 bits of generic pointer; apertures 4GiB-aligned).
__device__ __forceinline__ void lds_fadd(uint32_t byte_off, float v) {
    asm volatile("ds_add_f32 %0, %1" :: "v"(byte_off), "v"(v));
}

// ---- per-bin pixel counts (bins only); int atomics are native already ----
__global__ __launch_bounds__(256) void countk(const int* __restrict__ bins,
                                              int* __restrict__ counts) {
    __shared__ int hist[NCOPY * HSTR];
    const int t = threadIdx.x;
    for (int i = t; i < NCOPY * HSTR; i += 256) hist[i] = 0;
    __syncthreads();
    const int base = ((t >> 3) & 7) * HSTR;
    const int4* __restrict__ B4 = (const int4*)bins + blockIdx.x * 1024;
    #pragma unroll
    for (int g = 0; g < 4; ++g) {
        const int4 bb = B4[g * 256 + t];
        const int arr[4] = {bb.x, bb.y, bb.z, bb.w};
        int cb = -1, cnt = 0;
        #pragma unroll
        for (int m = 0; m < 4; ++m) {
            const int vb = (arr[m] > 3 && arr[m] < NBINS) ? arr[m] : -1;
            if (vb != cb) {
                if (cb >= 0) atomicAdd(&hist[base + cb], cnt);
                cb = vb; cnt = 0;
            }
            cnt += (vb >= 0) ? 1 : 0;
        }
        if (cb >= 0) atomicAdd(&hist[base + cb], cnt);
    }
    __syncthreads();
    int s = 0;
    #pragma unroll
    for (int c = 0; c < NCOPY; ++c) s += hist[c * HSTR + t];
    if (s) atomicAdd(&counts[t], s);
}

// ---- main pass: streaming loads + native ds_add_f32 scatter ----
__global__ __launch_bounds__(256) void pass(const float* __restrict__ parts,
                                            const float* __restrict__ projs,
                                            const int* __restrict__ bins,
                                            float* __restrict__ S1,
                                            float* __restrict__ S2) {
    __shared__ float h1[NCOPY * HSTR], h2[NCOPY * HSTR];
    const int t = threadIdx.x;
    for (int i = t; i < NCOPY * HSTR; i += 256) { h1[i] = 0.f; h2[i] = 0.f; }
    __syncthreads();

    const int chunk = blockIdx.x;
    const int b = blockIdx.y;
    // byte base of this thread's histogram copy (copy = (lane>>3)&7)
    const uint32_t h1b = (uint32_t)(uintptr_t)&h1[0] + ((t >> 3) & 7) * (HSTR * 4u);
    const uint32_t h2b = (uint32_t)(uintptr_t)&h2[0] + ((t >> 3) & 7) * (HSTR * 4u);

    const float4* __restrict__ P4 = (const float4*)(parts + (size_t)b * HW) + chunk * CPX4;
    const float4* __restrict__ Q4 = (const float4*)(projs + (size_t)b * HW) + chunk * CPX4;
    const int4*   __restrict__ B4 = (const int4*)bins + chunk * CPX4;

    #pragma unroll 2
    for (int g = 0; g < 8; ++g) {
        const int idx = g * 256 + t;
        const float4 p = P4[idx];
        const float4 q = Q4[idx];
        const int4  bb = B4[idx];
        const int   barr[4] = {bb.x, bb.y, bb.z, bb.w};
        const float narr[4] = {p.x - q.x, p.y - q.y, p.z - q.z, p.w - q.w};
        int cb = -1; float a1 = 0.f, a2 = 0.f;
        #pragma unroll
        for (int m = 0; m < 4; ++m) {
            const int vb = (barr[m] > 3 && barr[m] < NBINS) ? barr[m] : -1;
            if (vb != cb) {
                if (cb >= 0) {
                    lds_fadd(h1b + (uint32_t)cb * 4u, a1);
                    lds_fadd(h2b + (uint32_t)cb * 4u, a2);
                }
                cb = vb; a1 = 0.f; a2 = 0.f;
            }
            if (vb >= 0) { const float n = narr[m]; a1 += fabsf(n); a2 += n * n; }
        }
        if (cb >= 0) {
            lds_fadd(h1b + (uint32_t)cb * 4u, a1);
            lds_fadd(h2b + (uint32_t)cb * 4u, a2);
        }
    }
    // Drain our asm DS ops before the barrier: the compiler's waitcnt model
    // cannot see inline-asm ds_add_f32, so __syncthreads alone may skip the
    // lgkmcnt(0) drain.
    asm volatile("s_waitcnt lgkmcnt(0)" ::: "memory");
    __syncthreads();

    float v1 = 0.f, v2 = 0.f;
    #pragma unroll
    for (int c = 0; c < NCOPY; ++c) { v1 += h1[c * HSTR + t]; v2 += h2[c * HSTR + t]; }
    if (v1 != 0.f) unsafeAtomicAdd(&S1[b * NBINS + t], v1);
    if (v2 != 0.f) unsafeAtomicAdd(&S2[b * NBINS + t], v2);
}

// ---- finalize: per-batch closed-form sum over bins ----
__global__ __launch_bounds__(256) void finalize(const float* __restrict__ S1,
                                                const float* __restrict__ S2,
                                                const int* __restrict__ counts,
                                                float* __restrict__ out) {
    const int b = blockIdx.x;
    const int t = threadIdx.x;
    float contrib = 0.f;
    if (t > 3) {   // valid bins 4..255
        float c = (float)counts[t];
        float s1 = S1[b * NBINS + t];
        float s2 = S2[b * NBINS + t];
        float mean = s1 / fmaxf(c, 1.f);
        float ssq = fmaxf(s2 - mean * s1, 0.f);          // = sum (a - mean)^2
        float var = ssq / fmaxf(c - 1.f, 1.f);
        contrib = -0.5f * s2 / var - c * logf(6.283185307179586f * var);
    }
    #pragma unroll
    for (int off = 32; off > 0; off >>= 1) contrib += __shfl_down(contrib, off, 64);
    __shared__ float w[4];
    if ((t & 63) == 0) w[t >> 6] = contrib;
    __syncthreads();
    if (t == 0) out[b] = w[0] + w[1] + w[2] + w[3];
}

extern "C" void kernel_launch(void* const* d_in, const int* in_sizes, int n_in,
                              void* d_out, int out_size, void* d_ws, size_t ws_size,
                              hipStream_t stream) {
    const float* parts = (const float*)d_in[0];
    const float* projs = (const float*)d_in[1];
    const int* bins    = (const int*)d_in[2];
    float* out = (float*)d_out;

    char* ws = (char*)d_ws;
    int*   counts = (int*)(ws + 0);
    float* S1     = (float*)(ws + 1024);
    float* S2     = (float*)(ws + 132096);

    hipMemsetAsync(d_ws, 0, 263168, stream);
    countk  <<<64, 256, 0, stream>>>(bins, counts);          // 4096 px / block
    pass    <<<dim3(CHUNKS, NB), 256, 0, stream>>>(parts, projs, bins, S1, S2);
    finalize<<<NB, 256, 0, stream>>>(S1, S2, counts, out);
}